// Round 2
// baseline (4697.703 us; speedup 1.0000x reference)
//
#include <hip/hip_runtime.h>
#include <stdint.h>

#define NSTEPS 256
#define NHID   256
#define NG     768     // 3*NHID
#define BPB    8       // samples per block
#define TPB    1024
#define NSAMP  2048

__device__ __forceinline__ uint32_t rotl32(uint32_t v, int r){ return (v<<r)|(v>>(32-r)); }

// JAX threefry2x32 (exact): 20 rounds, key schedule injection every 4.
__device__ __forceinline__ void tf2x32(uint32_t k0, uint32_t k1,
                                       uint32_t x0, uint32_t x1,
                                       uint32_t& o0, uint32_t& o1){
  const uint32_t ks2 = k0 ^ k1 ^ 0x1BD11BDAu;
  x0 += k0; x1 += k1;
#define TF_R(r) { x0 += x1; x1 = rotl32(x1,(r)); x1 ^= x0; }
  TF_R(13) TF_R(15) TF_R(26) TF_R(6)
  x0 += k1;  x1 += ks2 + 1u;
  TF_R(17) TF_R(29) TF_R(16) TF_R(24)
  x0 += ks2; x1 += k0 + 2u;
  TF_R(13) TF_R(15) TF_R(26) TF_R(6)
  x0 += k0;  x1 += k1 + 3u;
  TF_R(17) TF_R(29) TF_R(16) TF_R(24)
  x0 += k1;  x1 += ks2 + 4u;
  TF_R(13) TF_R(15) TF_R(26) TF_R(6)
  x0 += ks2; x1 += k0 + 5u;
#undef TF_R
  o0 = x0; o1 = x1;
}

// XLA/Eigen f32 tanh: rational approx, clamp [-9,9], |x|<4e-4 -> x
__device__ __forceinline__ float tanh_xla(float x){
  float xc = fminf(fmaxf(x, -9.0f), 9.0f);
  float x2 = xc*xc;
  float p = -2.76076847742355e-16f;
  p = fmaf(p, x2, 2.00018790482477e-13f);
  p = fmaf(p, x2, -8.60467152213735e-11f);
  p = fmaf(p, x2, 5.12229709037114e-08f);
  p = fmaf(p, x2, 1.48572235717979e-05f);
  p = fmaf(p, x2, 6.37261928875436e-04f);
  p = fmaf(p, x2, 4.89352455891786e-03f);
  p = p * xc;
  float q = 1.19825839466702e-06f;
  q = fmaf(q, x2, 1.18534705686654e-04f);
  q = fmaf(q, x2, 2.26843463243900e-03f);
  q = fmaf(q, x2, 4.89352518554385e-03f);
  float r = p / q;
  return (fabsf(x) < 0.0004f) ? x : r;
}

__device__ __forceinline__ float sigmoid_ref(float x){
  return fmaf(0.5f, tanh_xla(0.5f*x), 0.5f);
}

__global__ __launch_bounds__(TPB) void rnn_sampler(
    const float* __restrict__ Wk,    // [2][768]
    const float* __restrict__ Wr,    // [256][768]
    const float* __restrict__ Bias,  // [2][768]  (b0 = x-bias, b1 = recurrent-bias)
    const float* __restrict__ Dk,    // [256][2]
    const float* __restrict__ Db,    // [2]
    float* __restrict__ out)         // [2048*256 samples as float][2048 logP]
{
  __shared__ float    h_lds[BPB][NHID];        // 8 KB
  __shared__ float    part[2][BPB][NG];        // 48 KB
  __shared__ uint32_t key0[NSTEPS];            // per-step key word 0
  __shared__ uint32_t key1[NSTEPS];            // per-step key word 1
  __shared__ int      xsel[BPB];               // 0 = zeros-x, 1/2 = one-hot(0/1)
  __shared__ float    logP[BPB];

  const int tid = threadIdx.x;
  const int b   = blockIdx.x;
  const int ks  = tid >> 8;     // k-slice 0..3 (64 k's each)
  const int col = tid & 255;    // gate-column group: owns col, col+256, col+512

  // ---- init: step keys (partitionable fold-like split: key_t = hash((0,42),(0,t)))
  if (tid < NSTEPS) {
    uint32_t o0, o1;
    tf2x32(0u, 42u, 0u, (uint32_t)tid, o0, o1);
    key0[tid] = o0; key1[tid] = o1;
  }
  for (int i = tid; i < BPB*NHID; i += TPB) (&h_lds[0][0])[i] = 0.0f;
  if (tid < BPB) { xsel[tid] = 0; logP[tid] = 0.0f; }
  __syncthreads();

  const int k0 = ks * 64;
  const float* wrp = Wr + (size_t)k0 * NG + col;

  for (int t = 0; t < NSTEPS; ++t) {
    // ================= Phase A: gh partials = h @ Wr (k-sliced) =================
    float acc[BPB][3];
#pragma unroll
    for (int s = 0; s < BPB; ++s) { acc[s][0]=0.f; acc[s][1]=0.f; acc[s][2]=0.f; }

#pragma unroll 2
    for (int kk = 0; kk < 64; kk += 4) {
      float w[4][3];
#pragma unroll
      for (int q = 0; q < 4; ++q) {
        const float* row = wrp + (size_t)(kk + q) * NG;
        w[q][0] = row[0]; w[q][1] = row[256]; w[q][2] = row[512];
      }
#pragma unroll
      for (int s = 0; s < BPB; ++s) {
        float4 h4 = *(const float4*)&h_lds[s][k0 + kk];   // wave-uniform broadcast
        acc[s][0] = fmaf(h4.x, w[0][0], acc[s][0]);
        acc[s][1] = fmaf(h4.x, w[0][1], acc[s][1]);
        acc[s][2] = fmaf(h4.x, w[0][2], acc[s][2]);
        acc[s][0] = fmaf(h4.y, w[1][0], acc[s][0]);
        acc[s][1] = fmaf(h4.y, w[1][1], acc[s][1]);
        acc[s][2] = fmaf(h4.y, w[1][2], acc[s][2]);
        acc[s][0] = fmaf(h4.z, w[2][0], acc[s][0]);
        acc[s][1] = fmaf(h4.z, w[2][1], acc[s][1]);
        acc[s][2] = fmaf(h4.z, w[2][2], acc[s][2]);
        acc[s][0] = fmaf(h4.w, w[3][0], acc[s][0]);
        acc[s][1] = fmaf(h4.w, w[3][1], acc[s][1]);
        acc[s][2] = fmaf(h4.w, w[3][2], acc[s][2]);
      }
    }
    // two-stage deterministic reduction: part[0]=ks0+ks2, part[1]=ks1+ks3
    if (ks >= 2) {
#pragma unroll
      for (int s = 0; s < BPB; ++s) {
        part[ks-2][s][col]     = acc[s][0];
        part[ks-2][s][col+256] = acc[s][1];
        part[ks-2][s][col+512] = acc[s][2];
      }
    }
    __syncthreads();
    if (ks < 2) {
#pragma unroll
      for (int s = 0; s < BPB; ++s) {
        part[ks][s][col]     += acc[s][0];
        part[ks][s][col+256] += acc[s][1];
        part[ks][s][col+512] += acc[s][2];
      }
    }
    __syncthreads();

    // ================= Phase B: gates -> h_new (2048 items / 1024 threads) ======
#pragma unroll
    for (int it = 0; it < 2; ++it) {
      int item = tid + it * TPB;          // 0..2047
      int s = item >> 8, n = item & 255;
      float ghz = (part[0][s][n]     + part[1][s][n])     + Bias[NG + n];
      float ghr = (part[0][s][n+256] + part[1][s][n+256]) + Bias[NG + n + 256];
      float ghn = (part[0][s][n+512] + part[1][s][n+512]) + Bias[NG + n + 512];
      int xs = xsel[s];
      float gxz, gxr, gxh;
      if (xs == 0) {
        gxz = Bias[n]; gxr = Bias[n+256]; gxh = Bias[n+512];
      } else {
        const float* wkrow = Wk + (size_t)(xs - 1) * NG;
        gxz = wkrow[n]     + Bias[n];
        gxr = wkrow[n+256] + Bias[n+256];
        gxh = wkrow[n+512] + Bias[n+512];
      }
      float z  = sigmoid_ref(gxz + ghz);
      float r  = sigmoid_ref(gxr + ghr);
      float hh = tanh_xla(gxh + r * ghn);
      float ho = h_lds[s][n];
      h_lds[s][n] = z * ho + (1.0f - z) * hh;
    }
    __syncthreads();

    // ================= Phase C: dense + softmax + categorical (wave per sample) =
    const int wid = tid >> 6, lane = tid & 63;
    if (wid < BPB) {
      const int s = wid;
      float4 h4 = *(const float4*)&h_lds[s][lane * 4];
      const float4* dk4 = (const float4*)(Dk + lane * 8);  // rows 4l..4l+3, 2 cols
      float4 d0 = dk4[0], d1 = dk4[1];
      float a0 = h4.x*d0.x + h4.y*d0.z + h4.z*d1.x + h4.w*d1.z;
      float a1 = h4.x*d0.y + h4.y*d0.w + h4.z*d1.y + h4.w*d1.w;
#pragma unroll
      for (int off = 32; off > 0; off >>= 1) {
        a0 += __shfl_down(a0, off);
        a1 += __shfl_down(a1, off);
      }
      if (lane == 0) {
        float l0 = a0 + Db[0], l1 = a1 + Db[1];
        float m  = fmaxf(l0, l1);
        float e0 = expf(l0 - m), e1 = expf(l1 - m);
        float sum = e0 + e1;
        float p0 = e0 / sum, p1 = e1 / sum;
        float lp0 = logf(1e-10f + p0), lp1 = logf(1e-10f + p1);

        const int i = b * BPB + s;
        const uint32_t kA = key0[t], kB = key1[t];
        // partitionable random_bits: element e of (2048,2) -> hash(key,(0,e)), bits = o0^o1
        uint32_t o0, o1;
        tf2x32(kA, kB, 0u, (uint32_t)(2*i),     o0, o1);
        uint32_t bits0 = o0 ^ o1;
        tf2x32(kA, kB, 0u, (uint32_t)(2*i + 1), o0, o1);
        uint32_t bits1 = o0 ^ o1;

        const float TINY = 1.17549435e-38f;
        float u0 = __uint_as_float((bits0 >> 9) | 0x3f800000u) - 1.0f;
        float u1 = __uint_as_float((bits1 >> 9) | 0x3f800000u) - 1.0f;
        u0 = fmaxf(TINY, u0 * (1.0f - TINY) + TINY);
        u1 = fmaxf(TINY, u1 * (1.0f - TINY) + TINY);
        float g0 = -logf(-logf(u0));
        float g1 = -logf(-logf(u1));

        float v0 = g0 + lp0, v1 = g1 + lp1;
        int st = (v1 > v0) ? 1 : 0;       // argmax, first-index tie-break
        logP[s] += st ? lp1 : lp0;
        xsel[s] = 1 + st;
        out[(size_t)i * NSTEPS + t] = (float)st;
      }
    }
    __syncthreads();
  }

  // ---- epilogue: logP stored as float32 (harness reads whole buffer as f32) ----
  if (tid < BPB) {
    const int i = b * BPB + tid;
    out[(size_t)NSAMP * NSTEPS + i] = logP[tid];
  }
}

extern "C" void kernel_launch(void* const* d_in, const int* in_sizes, int n_in,
                              void* d_out, int out_size, void* d_ws, size_t ws_size,
                              hipStream_t stream) {
  const float* Wk = (const float*)d_in[0];  // gru_kernel     [2,768]
  const float* Wr = (const float*)d_in[1];  // gru_rec_kernel [256,768]
  const float* B  = (const float*)d_in[2];  // gru_bias       [2,768]
  const float* Dk = (const float*)d_in[3];  // dense_kernel   [256,2]
  const float* Db = (const float*)d_in[4];  // dense_bias     [2]
  float* out = (float*)d_out;
  rnn_sampler<<<dim3(NSAMP / BPB), dim3(TPB), 0, stream>>>(Wk, Wr, B, Dk, Db, out);
}

// Round 3
// 3393.456 us; speedup vs baseline: 1.3843x; 1.3843x over previous
//
#include <hip/hip_runtime.h>
#include <stdint.h>

#define NSTEPS 256
#define NHID   256
#define NG     768     // 3*NHID
#define BPB    8       // samples per block
#define TPB    768     // 12 waves: 4 k-slices x 192 col-quads
#define NSAMP  2048

__device__ __forceinline__ uint32_t rotl32(uint32_t v, int r){ return (v<<r)|(v>>(32-r)); }

// JAX threefry2x32 (exact): 20 rounds, key schedule injection every 4.
__device__ __forceinline__ void tf2x32(uint32_t k0, uint32_t k1,
                                       uint32_t x0, uint32_t x1,
                                       uint32_t& o0, uint32_t& o1){
  const uint32_t ks2 = k0 ^ k1 ^ 0x1BD11BDAu;
  x0 += k0; x1 += k1;
#define TF_R(r) { x0 += x1; x1 = rotl32(x1,(r)); x1 ^= x0; }
  TF_R(13) TF_R(15) TF_R(26) TF_R(6)
  x0 += k1;  x1 += ks2 + 1u;
  TF_R(17) TF_R(29) TF_R(16) TF_R(24)
  x0 += ks2; x1 += k0 + 2u;
  TF_R(13) TF_R(15) TF_R(26) TF_R(6)
  x0 += k0;  x1 += k1 + 3u;
  TF_R(17) TF_R(29) TF_R(16) TF_R(24)
  x0 += k1;  x1 += ks2 + 4u;
  TF_R(13) TF_R(15) TF_R(26) TF_R(6)
  x0 += ks2; x1 += k0 + 5u;
#undef TF_R
  o0 = x0; o1 = x1;
}

// XLA/Eigen f32 tanh: rational approx, clamp [-9,9], |x|<4e-4 -> x
__device__ __forceinline__ float tanh_xla(float x){
  float xc = fminf(fmaxf(x, -9.0f), 9.0f);
  float x2 = xc*xc;
  float p = -2.76076847742355e-16f;
  p = fmaf(p, x2, 2.00018790482477e-13f);
  p = fmaf(p, x2, -8.60467152213735e-11f);
  p = fmaf(p, x2, 5.12229709037114e-08f);
  p = fmaf(p, x2, 1.48572235717979e-05f);
  p = fmaf(p, x2, 6.37261928875436e-04f);
  p = fmaf(p, x2, 4.89352455891786e-03f);
  p = p * xc;
  float q = 1.19825839466702e-06f;
  q = fmaf(q, x2, 1.18534705686654e-04f);
  q = fmaf(q, x2, 2.26843463243900e-03f);
  q = fmaf(q, x2, 4.89352518554385e-03f);
  float r = p / q;
  return (fabsf(x) < 0.0004f) ? x : r;
}

__device__ __forceinline__ float sigmoid_ref(float x){
  return fmaf(0.5f, tanh_xla(0.5f*x), 0.5f);
}

__global__ __launch_bounds__(TPB, 3) void rnn_sampler(
    const float* __restrict__ Wk,    // [2][768]
    const float* __restrict__ Wr,    // [256][768]
    const float* __restrict__ Bias,  // [2][768]
    const float* __restrict__ Dk,    // [256][2]
    const float* __restrict__ Db,    // [2]
    float* __restrict__ out)         // [2048*256 samples as float][2048 logP]
{
  __shared__ float    h_lds[BPB][NHID];        // 8 KB
  __shared__ float    part[2][BPB][NG];        // 48 KB
  __shared__ uint32_t key0[NSTEPS];            // 1 KB
  __shared__ uint32_t key1[NSTEPS];            // 1 KB
  __shared__ int      xsel[BPB];
  __shared__ float    logP[BPB];

  const int tid  = threadIdx.x;
  const int b    = blockIdx.x;
  const int ks   = tid / 192;     // k-slice 0..3 (64 k's each), wave-uniform
  const int cq   = tid % 192;     // column-quad: abs cols 4cq..4cq+3
  const int wid  = tid >> 6;
  const int lane = tid & 63;

  // ---- init: step keys (partitionable fold-like split: key_t = hash((0,42),(0,t)))
  if (tid < NSTEPS) {
    uint32_t o0, o1;
    tf2x32(0u, 42u, 0u, (uint32_t)tid, o0, o1);
    key0[tid] = o0; key1[tid] = o1;
  }
  for (int i = tid; i < BPB*NHID; i += TPB) (&h_lds[0][0])[i] = 0.0f;
  if (tid < BPB) { xsel[tid] = 0; logP[tid] = 0.0f; }
  __syncthreads();

  const int k0 = ks * 64;
  const float* wp = Wr + (size_t)k0 * NG + 4*cq;
  float4 acc[BPB];

  for (int t = 0; t <= NSTEPS; ++t) {
    // ===== Phase C for step t-1 (waves 0-7), overlapped with Phase A(t) on others
    if (t > 0 && wid < BPB) {
      const int tc = t - 1;
      const int s  = wid;
      float4 h4 = *(const float4*)&h_lds[s][lane * 4];
      const float4* dk4 = (const float4*)(Dk + lane * 8);
      float4 d0 = dk4[0], d1 = dk4[1];
      float a0 = h4.x*d0.x + h4.y*d0.z + h4.z*d1.x + h4.w*d1.z;
      float a1 = h4.x*d0.y + h4.y*d0.w + h4.z*d1.y + h4.w*d1.w;
#pragma unroll
      for (int off = 32; off > 0; off >>= 1) {
        a0 += __shfl_down(a0, off);
        a1 += __shfl_down(a1, off);
      }
      if (lane == 0) {
        float l0 = a0 + Db[0], l1 = a1 + Db[1];
        float m  = fmaxf(l0, l1);
        float e0 = expf(l0 - m), e1 = expf(l1 - m);
        float sum = e0 + e1;
        float p0 = e0 / sum, p1 = e1 / sum;
        float lp0 = logf(1e-10f + p0), lp1 = logf(1e-10f + p1);

        const int i = b * BPB + s;
        const uint32_t kA = key0[tc], kB = key1[tc];
        uint32_t o0, o1;
        tf2x32(kA, kB, 0u, (uint32_t)(2*i),     o0, o1);
        uint32_t bits0 = o0 ^ o1;
        tf2x32(kA, kB, 0u, (uint32_t)(2*i + 1), o0, o1);
        uint32_t bits1 = o0 ^ o1;

        const float TINY = 1.17549435e-38f;
        float u0 = __uint_as_float((bits0 >> 9) | 0x3f800000u) - 1.0f;
        float u1 = __uint_as_float((bits1 >> 9) | 0x3f800000u) - 1.0f;
        u0 = fmaxf(TINY, u0 * (1.0f - TINY) + TINY);
        u1 = fmaxf(TINY, u1 * (1.0f - TINY) + TINY);
        float g0 = -logf(-logf(u0));
        float g1 = -logf(-logf(u1));

        float v0 = g0 + lp0, v1 = g1 + lp1;
        int st = (v1 > v0) ? 1 : 0;
        logP[s] += st ? lp1 : lp0;
        xsel[s] = 1 + st;
        out[(size_t)i * NSTEPS + tc] = (float)st;
      }
    }
    if (t == NSTEPS) break;

    // ===== Phase A: gh partials = h @ Wr, k-sliced, float4-coalesced W loads ====
#pragma unroll
    for (int s = 0; s < BPB; ++s) acc[s] = make_float4(0.f, 0.f, 0.f, 0.f);

#pragma unroll 2
    for (int kk = 0; kk < 64; kk += 4) {
      const float* rp = wp + (size_t)kk * NG;
      float4 w0 = *(const float4*)(rp);
      float4 w1 = *(const float4*)(rp + NG);
      float4 w2 = *(const float4*)(rp + 2*NG);
      float4 w3 = *(const float4*)(rp + 3*NG);
#pragma unroll
      for (int s = 0; s < BPB; ++s) {
        float4 h4 = *(const float4*)&h_lds[s][k0 + kk];
        acc[s].x = fmaf(h4.x, w0.x, acc[s].x);
        acc[s].y = fmaf(h4.x, w0.y, acc[s].y);
        acc[s].z = fmaf(h4.x, w0.z, acc[s].z);
        acc[s].w = fmaf(h4.x, w0.w, acc[s].w);
        acc[s].x = fmaf(h4.y, w1.x, acc[s].x);
        acc[s].y = fmaf(h4.y, w1.y, acc[s].y);
        acc[s].z = fmaf(h4.y, w1.z, acc[s].z);
        acc[s].w = fmaf(h4.y, w1.w, acc[s].w);
        acc[s].x = fmaf(h4.z, w2.x, acc[s].x);
        acc[s].y = fmaf(h4.z, w2.y, acc[s].y);
        acc[s].z = fmaf(h4.z, w2.z, acc[s].z);
        acc[s].w = fmaf(h4.z, w2.w, acc[s].w);
        acc[s].x = fmaf(h4.w, w3.x, acc[s].x);
        acc[s].y = fmaf(h4.w, w3.y, acc[s].y);
        acc[s].z = fmaf(h4.w, w3.z, acc[s].z);
        acc[s].w = fmaf(h4.w, w3.w, acc[s].w);
      }
    }
    // two-stage deterministic reduction: part[0]=ks2+ks0, part[1]=ks3+ks1
    if (ks >= 2) {
#pragma unroll
      for (int s = 0; s < BPB; ++s)
        *(float4*)&part[ks-2][s][4*cq] = acc[s];
    }
    __syncthreads();
    if (ks < 2) {
#pragma unroll
      for (int s = 0; s < BPB; ++s) {
        float4 p = *(const float4*)&part[ks][s][4*cq];
        p.x += acc[s].x; p.y += acc[s].y; p.z += acc[s].z; p.w += acc[s].w;
        *(float4*)&part[ks][s][4*cq] = p;
      }
    }
    __syncthreads();

    // ===== Phase B: gates -> h_new (2048 items / 768 threads) ==================
    for (int item = tid; item < NSAMP; item += TPB) {
      int s = item >> 8, n = item & 255;
      float ghz = (part[0][s][n]     + part[1][s][n])     + Bias[NG + n];
      float ghr = (part[0][s][n+256] + part[1][s][n+256]) + Bias[NG + n + 256];
      float ghn = (part[0][s][n+512] + part[1][s][n+512]) + Bias[NG + n + 512];
      int xs = xsel[s];
      float gxz, gxr, gxh;
      if (xs == 0) {
        gxz = Bias[n]; gxr = Bias[n+256]; gxh = Bias[n+512];
      } else {
        const float* wkrow = Wk + (size_t)(xs - 1) * NG;
        gxz = wkrow[n]     + Bias[n];
        gxr = wkrow[n+256] + Bias[n+256];
        gxh = wkrow[n+512] + Bias[n+512];
      }
      float z  = sigmoid_ref(gxz + ghz);
      float r  = sigmoid_ref(gxr + ghr);
      float hh = tanh_xla(gxh + r * ghn);
      float ho = h_lds[s][n];
      h_lds[s][n] = z * ho + (1.0f - z) * hh;
    }
    __syncthreads();
  }

  __syncthreads();   // logP[s] written by wave s lane 0 during final Phase C

  // ---- epilogue: logP as float32 ----
  if (tid < BPB) {
    const int i = b * BPB + tid;
    out[(size_t)NSAMP * NSTEPS + i] = logP[tid];
  }
}

extern "C" void kernel_launch(void* const* d_in, const int* in_sizes, int n_in,
                              void* d_out, int out_size, void* d_ws, size_t ws_size,
                              hipStream_t stream) {
  const float* Wk = (const float*)d_in[0];  // gru_kernel     [2,768]
  const float* Wr = (const float*)d_in[1];  // gru_rec_kernel [256,768]
  const float* B  = (const float*)d_in[2];  // gru_bias       [2,768]
  const float* Dk = (const float*)d_in[3];  // dense_kernel   [256,2]
  const float* Db = (const float*)d_in[4];  // dense_bias     [2]
  float* out = (float*)d_out;
  rnn_sampler<<<dim3(NSAMP / BPB), dim3(TPB), 0, stream>>>(Wk, Wr, B, Dk, Db, out);
}

// Round 4
// 3139.656 us; speedup vs baseline: 1.4962x; 1.0808x over previous
//
#include <hip/hip_runtime.h>
#include <stdint.h>

#define NSTEPS 256
#define NHID   256
#define NG     768     // 3*NHID
#define BPB    8       // samples per block
#define TPB    768     // 12 waves: 4 k-slices x 192 col-quads
#define NSAMP  2048

__device__ __forceinline__ uint32_t rotl32(uint32_t v, int r){ return (v<<r)|(v>>(32-r)); }

// JAX threefry2x32 (exact): 20 rounds, key schedule injection every 4.
__device__ __forceinline__ void tf2x32(uint32_t k0, uint32_t k1,
                                       uint32_t x0, uint32_t x1,
                                       uint32_t& o0, uint32_t& o1){
  const uint32_t ks2 = k0 ^ k1 ^ 0x1BD11BDAu;
  x0 += k0; x1 += k1;
#define TF_R(r) { x0 += x1; x1 = rotl32(x1,(r)); x1 ^= x0; }
  TF_R(13) TF_R(15) TF_R(26) TF_R(6)
  x0 += k1;  x1 += ks2 + 1u;
  TF_R(17) TF_R(29) TF_R(16) TF_R(24)
  x0 += ks2; x1 += k0 + 2u;
  TF_R(13) TF_R(15) TF_R(26) TF_R(6)
  x0 += k0;  x1 += k1 + 3u;
  TF_R(17) TF_R(29) TF_R(16) TF_R(24)
  x0 += k1;  x1 += ks2 + 4u;
  TF_R(13) TF_R(15) TF_R(26) TF_R(6)
  x0 += ks2; x1 += k0 + 5u;
#undef TF_R
  o0 = x0; o1 = x1;
}

// XLA/Eigen f32 tanh: rational approx, clamp [-9,9], |x|<4e-4 -> x
__device__ __forceinline__ float tanh_xla(float x){
  float xc = fminf(fmaxf(x, -9.0f), 9.0f);
  float x2 = xc*xc;
  float p = -2.76076847742355e-16f;
  p = fmaf(p, x2, 2.00018790482477e-13f);
  p = fmaf(p, x2, -8.60467152213735e-11f);
  p = fmaf(p, x2, 5.12229709037114e-08f);
  p = fmaf(p, x2, 1.48572235717979e-05f);
  p = fmaf(p, x2, 6.37261928875436e-04f);
  p = fmaf(p, x2, 4.89352455891786e-03f);
  p = p * xc;
  float q = 1.19825839466702e-06f;
  q = fmaf(q, x2, 1.18534705686654e-04f);
  q = fmaf(q, x2, 2.26843463243900e-03f);
  q = fmaf(q, x2, 4.89352518554385e-03f);
  float r = p / q;
  return (fabsf(x) < 0.0004f) ? x : r;
}

__device__ __forceinline__ float sigmoid_ref(float x){
  return fmaf(0.5f, tanh_xla(0.5f*x), 0.5f);
}

// Per-group FMA: order preserved exactly (h.x*row0, h.y*row1, h.z*row2, h.w*row3)
__device__ __forceinline__ void gfma(float4 h, float4 w0, float4 w1, float4 w2, float4 w3, float4& a){
  a.x = fmaf(h.x, w0.x, a.x); a.y = fmaf(h.x, w0.y, a.y);
  a.z = fmaf(h.x, w0.z, a.z); a.w = fmaf(h.x, w0.w, a.w);
  a.x = fmaf(h.y, w1.x, a.x); a.y = fmaf(h.y, w1.y, a.y);
  a.z = fmaf(h.y, w1.z, a.z); a.w = fmaf(h.y, w1.w, a.w);
  a.x = fmaf(h.z, w2.x, a.x); a.y = fmaf(h.z, w2.y, a.y);
  a.z = fmaf(h.z, w2.z, a.z); a.w = fmaf(h.z, w2.w, a.w);
  a.x = fmaf(h.w, w3.x, a.x); a.y = fmaf(h.w, w3.y, a.y);
  a.z = fmaf(h.w, w3.z, a.z); a.w = fmaf(h.w, w3.w, a.w);
}

__global__ __launch_bounds__(TPB, 3) void rnn_sampler(
    const float* __restrict__ Wk,    // [2][768]
    const float* __restrict__ Wr,    // [256][768]
    const float* __restrict__ Bias,  // [2][768]
    const float* __restrict__ Dk,    // [256][2]
    const float* __restrict__ Db,    // [2]
    float* __restrict__ out)         // [2048*256 samples as float][2048 logP]
{
  __shared__ float    h_lds[BPB][NHID];        // 8 KB
  __shared__ float    part[4][BPB][NG];        // 96 KB — raw per-slice partials
  __shared__ uint32_t key0[NSTEPS];            // 1 KB
  __shared__ uint32_t key1[NSTEPS];            // 1 KB
  __shared__ float    wk_lds[2*NG];            // 6 KB
  __shared__ float    bias_lds[2*NG];          // 6 KB
  __shared__ float    dk_lds[NHID*2];          // 2 KB
  __shared__ float    db_lds[2];
  __shared__ int      xsel[BPB];
  __shared__ float    logPs[BPB];

  const int tid  = threadIdx.x;
  const int b    = blockIdx.x;
  const int ks   = tid / 192;     // k-slice 0..3 (64 k's each), wave-uniform
  const int cq   = tid % 192;     // column-quad: abs cols 4cq..4cq+3
  const int wid  = tid >> 6;
  const int lane = tid & 63;

  // ---- init: step keys + LDS copies of small weights ----
  if (tid < NSTEPS) {
    uint32_t o0, o1;
    tf2x32(0u, 42u, 0u, (uint32_t)tid, o0, o1);
    key0[tid] = o0; key1[tid] = o1;
  }
  for (int i = tid; i < BPB*NHID; i += TPB) (&h_lds[0][0])[i] = 0.0f;
  for (int i = tid; i < 2*NG; i += TPB) { wk_lds[i] = Wk[i]; bias_lds[i] = Bias[i]; }
  for (int i = tid; i < NHID*2; i += TPB) dk_lds[i] = Dk[i];
  if (tid < 2) db_lds[tid] = Db[tid];
  if (tid < BPB) { xsel[tid] = 0; logPs[tid] = 0.0f; }
  __syncthreads();

  const int k0 = ks * 64;
  const float* wp = Wr + (size_t)k0 * NG + 4*cq;
  float4 acc[BPB];

  for (int t = 0; t <= NSTEPS; ++t) {
    // ===== Phase C for step t-1 (waves 0-7), overlapped with Phase A(t) =====
    if (t > 0 && wid < BPB) {
      const int tc = t - 1;
      const int s  = wid;
      float4 h4 = *(const float4*)&h_lds[s][lane * 4];
      float4 d0 = *(const float4*)&dk_lds[lane * 8];
      float4 d1 = *(const float4*)&dk_lds[lane * 8 + 4];
      float a0 = h4.x*d0.x + h4.y*d0.z + h4.z*d1.x + h4.w*d1.z;
      float a1 = h4.x*d0.y + h4.y*d0.w + h4.z*d1.y + h4.w*d1.w;
#pragma unroll
      for (int off = 32; off > 0; off >>= 1) {
        a0 += __shfl_down(a0, off);
        a1 += __shfl_down(a1, off);
      }
      // lanes 0 and 1 each compute the gumbel for their own index (pure int->float,
      // bit-identical on any lane); lane 0 pulls lane 1's result.
      float gv = 0.0f;
      if (lane < 2) {
        const int i = b * BPB + s;
        uint32_t o0, o1;
        tf2x32(key0[tc], key1[tc], 0u, (uint32_t)(2*i + lane), o0, o1);
        uint32_t bits = o0 ^ o1;
        const float TINY = 1.17549435e-38f;
        float u = __uint_as_float((bits >> 9) | 0x3f800000u) - 1.0f;
        u = fmaxf(TINY, u * (1.0f - TINY) + TINY);
        gv = -logf(-logf(u));
      }
      float g1 = __shfl(gv, 1);
      if (lane == 0) {
        float l0 = a0 + db_lds[0], l1 = a1 + db_lds[1];
        float m  = fmaxf(l0, l1);
        float e0 = expf(l0 - m), e1 = expf(l1 - m);
        float sum = e0 + e1;
        float p0 = e0 / sum, p1 = e1 / sum;
        float lp0 = logf(1e-10f + p0), lp1 = logf(1e-10f + p1);
        float v0 = gv + lp0, v1 = g1 + lp1;
        int st = (v1 > v0) ? 1 : 0;
        logPs[s] += st ? lp1 : lp0;
        xsel[s] = 1 + st;
        const int i = b * BPB + s;
        out[(size_t)i * NSTEPS + tc] = (float)st;
      }
    }
    if (t == NSTEPS) break;

    // ===== Phase A: gh partials = h @ Wr, double-buffered W and h ===========
#pragma unroll
    for (int s = 0; s < BPB; ++s) acc[s] = make_float4(0.f, 0.f, 0.f, 0.f);

    float4 wA0, wA1, wA2, wA3, wB0, wB1, wB2, wB3;
    float4 hA[BPB], hB[BPB];
    {
      const float* rp = wp;
      wA0 = *(const float4*)(rp);
      wA1 = *(const float4*)(rp + NG);
      wA2 = *(const float4*)(rp + 2*NG);
      wA3 = *(const float4*)(rp + 3*NG);
    }
#pragma unroll
    for (int s = 0; s < BPB; ++s) hA[s] = *(const float4*)&h_lds[s][k0];

    for (int g = 0; g < 16; g += 2) {
      {
        const float* rp = wp + (size_t)((g + 1) * 4) * NG;
        wB0 = *(const float4*)(rp);
        wB1 = *(const float4*)(rp + NG);
        wB2 = *(const float4*)(rp + 2*NG);
        wB3 = *(const float4*)(rp + 3*NG);
      }
#pragma unroll
      for (int s = 0; s < BPB; ++s) hB[s] = *(const float4*)&h_lds[s][k0 + 4*(g+1)];
#pragma unroll
      for (int s = 0; s < BPB; ++s) gfma(hA[s], wA0, wA1, wA2, wA3, acc[s]);

      const int g2 = (g + 2 < 16) ? (g + 2) : 0;   // wrap dummy prefetch, stays in-bounds
      {
        const float* rp = wp + (size_t)(g2 * 4) * NG;
        wA0 = *(const float4*)(rp);
        wA1 = *(const float4*)(rp + NG);
        wA2 = *(const float4*)(rp + 2*NG);
        wA3 = *(const float4*)(rp + 3*NG);
      }
#pragma unroll
      for (int s = 0; s < BPB; ++s) hA[s] = *(const float4*)&h_lds[s][k0 + 4*g2];
#pragma unroll
      for (int s = 0; s < BPB; ++s) gfma(hB[s], wB0, wB1, wB2, wB3, acc[s]);
    }

    // raw per-slice write — single barrier, no read-modify-write
#pragma unroll
    for (int s = 0; s < BPB; ++s)
      *(float4*)&part[ks][s][4*cq] = acc[s];
    __syncthreads();

    // ===== Phase B: gates -> h_new (2048 items; 3rd pass on tid>=256) =======
#pragma unroll
    for (int it = 0; it < 3; ++it) {
      int item;
      if (it == 0)      item = tid;
      else if (it == 1) item = tid + TPB;
      else {
        if (tid < 256) break;
        item = 1280 + tid;           // 1536..2047
      }
      int s = item >> 8, n = item & 255;
      float ghz = ((part[0][s][n]     + part[2][s][n])     + (part[1][s][n]     + part[3][s][n]))     + bias_lds[NG + n];
      float ghr = ((part[0][s][n+256] + part[2][s][n+256]) + (part[1][s][n+256] + part[3][s][n+256])) + bias_lds[NG + n + 256];
      float ghn = ((part[0][s][n+512] + part[2][s][n+512]) + (part[1][s][n+512] + part[3][s][n+512])) + bias_lds[NG + n + 512];
      int xs = xsel[s];
      float gxz, gxr, gxh;
      if (xs == 0) {
        gxz = bias_lds[n]; gxr = bias_lds[n+256]; gxh = bias_lds[n+512];
      } else {
        const float* wkrow = wk_lds + (xs - 1) * NG;
        gxz = wkrow[n]     + bias_lds[n];
        gxr = wkrow[n+256] + bias_lds[n+256];
        gxh = wkrow[n+512] + bias_lds[n+512];
      }
      float z  = sigmoid_ref(gxz + ghz);
      float r  = sigmoid_ref(gxr + ghr);
      float hh = tanh_xla(gxh + r * ghn);
      float ho = h_lds[s][n];
      h_lds[s][n] = z * ho + (1.0f - z) * hh;
    }
    __syncthreads();
  }

  __syncthreads();   // logPs[s] written by wave s lane 0 during final Phase C

  // ---- epilogue: logP as float32 ----
  if (tid < BPB) {
    const int i = b * BPB + tid;
    out[(size_t)NSAMP * NSTEPS + i] = logPs[tid];
  }
}

extern "C" void kernel_launch(void* const* d_in, const int* in_sizes, int n_in,
                              void* d_out, int out_size, void* d_ws, size_t ws_size,
                              hipStream_t stream) {
  const float* Wk = (const float*)d_in[0];  // gru_kernel     [2,768]
  const float* Wr = (const float*)d_in[1];  // gru_rec_kernel [256,768]
  const float* B  = (const float*)d_in[2];  // gru_bias       [2,768]
  const float* Dk = (const float*)d_in[3];  // dense_kernel   [256,2]
  const float* Db = (const float*)d_in[4];  // dense_bias     [2]
  float* out = (float*)d_out;
  rnn_sampler<<<dim3(NSAMP / BPB), dim3(TPB), 0, stream>>>(Wk, Wr, B, Dk, Db, out);
}